// Round 7
// baseline (100.860 us; speedup 1.0000x reference)
//
#include <hip/hip_runtime.h>

// RoPE with on-the-fly trig, MONOLITHIC launch, 8 floats/thread:
// 32768 blocks x 256 threads, no loop. Each thread issues pos + two
// independent dwordx4 loads at birth (doubling bytes-in-flight per wave
// vs the 4-float version), computes 4 sin/cos pairs, stores 32 B.
// Compulsory traffic: 256 MB read + 256 MB write + 2 MB pos -> 82.4 us
// floor at the 6.29 TB/s measured float4-copy ceiling (m13).

typedef float f32x4 __attribute__((ext_vector_type(4)));

__global__ __launch_bounds__(256)
void rope_kernel(const float* __restrict__ x,
                 const int* __restrict__ pos,
                 float* __restrict__ out) {
    int g = blockIdx.x * 256 + threadIdx.x;   // one 8-float chunk per thread
    int row = g >> 4;                         // 16 chunks per 128-elem row
    int p = pos[row];                         // issue ASAP; bcast across 16 lanes
    const f32x4* xp = reinterpret_cast<const f32x4*>(x) + 2ll * g;
    f32x4 v0 = xp[0];                         // two independent 16B loads in flight
    f32x4 v1 = xp[1];

    const float K = 0.20762051f;              // log2(10000)/64
    const float INV2PI = 0.15915494309189535f;
    int i0 = (g & 15) << 2;                   // first pair index: 0,4,...,60
    float ifr0 = exp2f(-(float)(i0    ) * K) * INV2PI;  // overlaps the loads
    float ifr1 = exp2f(-(float)(i0 + 1) * K) * INV2PI;
    float ifr2 = exp2f(-(float)(i0 + 2) * K) * INV2PI;
    float ifr3 = exp2f(-(float)(i0 + 3) * K) * INV2PI;

    float pf = (float)p;
    float a0 = __builtin_amdgcn_fractf(pf * ifr0);      // revolutions in [0,1)
    float a1 = __builtin_amdgcn_fractf(pf * ifr1);
    float a2 = __builtin_amdgcn_fractf(pf * ifr2);
    float a3 = __builtin_amdgcn_fractf(pf * ifr3);
    float s0 = __builtin_amdgcn_sinf(a0), c0 = __builtin_amdgcn_cosf(a0);
    float s1 = __builtin_amdgcn_sinf(a1), c1 = __builtin_amdgcn_cosf(a1);
    float s2 = __builtin_amdgcn_sinf(a2), c2 = __builtin_amdgcn_cosf(a2);
    float s3 = __builtin_amdgcn_sinf(a3), c3 = __builtin_amdgcn_cosf(a3);

    f32x4 r0, r1;
    r0.x = c0 * v0.x - s0 * v0.y;  r0.y = s0 * v0.x + c0 * v0.y;
    r0.z = c1 * v0.z - s1 * v0.w;  r0.w = s1 * v0.z + c1 * v0.w;
    r1.x = c2 * v1.x - s2 * v1.y;  r1.y = s2 * v1.x + c2 * v1.y;
    r1.z = c3 * v1.z - s3 * v1.w;  r1.w = s3 * v1.z + c3 * v1.w;

    f32x4* op = reinterpret_cast<f32x4*>(out) + 2ll * g;
    op[0] = r0;
    op[1] = r1;
}

extern "C" void kernel_launch(void* const* d_in, const int* in_sizes, int n_in,
                              void* d_out, int out_size, void* d_ws, size_t ws_size,
                              hipStream_t stream) {
    const float* x   = (const float*)d_in[0];
    const int*   pos = (const int*)d_in[3];
    float* out = (float*)d_out;

    int n8 = out_size / 8;                 // 8,388,608 chunks of 8 floats
    const int block = 256;
    int grid = n8 / block;                 // 32768 blocks, exact
    rope_kernel<<<grid, block, 0, stream>>>(x, pos, out);
}